// Round 11
// baseline (63.406 us; speedup 1.0000x reference)
//
#include <hip/hip_runtime.h>

// Segmented mean over sorted segment ids, two-kernel plan (round-9 winner +
// nt prepass loads + int2 boundary load):
//   K1 (boundary pre-pass, int4-vectorized, nontemporal id loads):
//       offs[s] = lower_bound(seg_ids, s) for s in [0, N], O(E), no searches.
//   K2 (stream): one wave per segment. Boundaries read as ONE int2. 8-deep
//       batched PREDICATED nontemporal loads (rows start+(t>>4)+4k, k=0..7,
//       col (t&15)*4) issued before any use -> one effective vmcnt stall per
//       avg segment (25 rows ~ 6.25 groups), then tree-sum. shfl_xor(16|32)
//       fold; lanes 0..15 store one float4.
// ws usage: (N+1) ints = 200 KB.

#define WPB 4   // waves per block

typedef float f4 __attribute__((ext_vector_type(4)));
typedef int   i4 __attribute__((ext_vector_type(4)));
typedef int   i2 __attribute__((ext_vector_type(2)));

__global__ __launch_bounds__(256) void seg_bounds_kernel(
    const int* __restrict__ seg_ids,
    int*       __restrict__ offs,   // [N+1]
    int E, int N)
{
    const int q    = blockIdx.x * blockDim.x + threadIdx.x;  // quad index
    const int base = q << 2;
    if (base >= E) return;

    int id0, id1, id2, id3;
    int nv = E - base;                       // >=1
    if (nv >= 4) {
        const i4 v = __builtin_nontemporal_load(
            reinterpret_cast<const i4*>(seg_ids + base));
        id0 = v.x; id1 = v.y; id2 = v.z; id3 = v.w;
    } else {
        id0 = seg_ids[base];
        id1 = (nv > 1) ? seg_ids[base + 1] : id0;
        id2 = (nv > 2) ? seg_ids[base + 2] : id1;
        id3 = id2;
    }

    int prev = (base > 0) ? seg_ids[base - 1] : -1;

    // first row of every segment in (prev, id_j] is base+j
    for (int s = prev + 1; s <= id0; ++s) offs[s] = base + 0;
    if (nv > 1) for (int s = id0 + 1; s <= id1; ++s) offs[s] = base + 1;
    if (nv > 2) for (int s = id1 + 1; s <= id2; ++s) offs[s] = base + 2;
    if (nv > 3) for (int s = id2 + 1; s <= id3; ++s) offs[s] = base + 3;

    if (base + 4 >= E) {                     // last quad fills the tail
        for (int s = id3 + 1; s <= N; ++s) offs[s] = E;
    }
}

__global__ __launch_bounds__(256) void seg_mean_kernel(
    const float* __restrict__ values,
    const int*   __restrict__ offs,
    float*       __restrict__ out,
    int N)
{
    const int wave = threadIdx.x >> 6;
    const int s    = blockIdx.x * WPB + wave;    // one segment per wave
    if (s >= N) return;

    const int t = threadIdx.x & 63;

    // one 8B load for both boundaries (offs has N+1 entries, s+1 <= N valid)
    const i2 b = *reinterpret_cast<const i2*>(offs + s);
    const int start = b.x;
    const int end   = b.y;
    const int count = end - start;

    const int rsub = t >> 4;          // row-in-group-of-4: 0..3
    const int c4   = (t & 15) << 2;   // column base: 0,4,...,60

    // lane t covers rows start+(t>>4)+4k, cols (t&15)*4 .. +3
    const f4* p = reinterpret_cast<const f4*>(
        values + (size_t)start * 64 + (t << 2));

    f4 acc = {0.f, 0.f, 0.f, 0.f};
    int r = start + rsub;

    while (r < end) {
        // batch-issue up to 8 predicated group loads, then one tree-sum.
        f4 v0 = {0.f,0.f,0.f,0.f}, v1 = {0.f,0.f,0.f,0.f};
        f4 v2 = {0.f,0.f,0.f,0.f}, v3 = {0.f,0.f,0.f,0.f};
        f4 v4 = {0.f,0.f,0.f,0.f}, v5 = {0.f,0.f,0.f,0.f};
        f4 v6 = {0.f,0.f,0.f,0.f}, v7 = {0.f,0.f,0.f,0.f};

        v0 = __builtin_nontemporal_load(p);          // r < end guaranteed
        if (r +  4 < end) v1 = __builtin_nontemporal_load(p +  64);
        if (r +  8 < end) v2 = __builtin_nontemporal_load(p + 128);
        if (r + 12 < end) v3 = __builtin_nontemporal_load(p + 192);
        if (r + 16 < end) v4 = __builtin_nontemporal_load(p + 256);
        if (r + 20 < end) v5 = __builtin_nontemporal_load(p + 320);
        if (r + 24 < end) v6 = __builtin_nontemporal_load(p + 384);
        if (r + 28 < end) v7 = __builtin_nontemporal_load(p + 448);

        acc += ((v0 + v1) + (v2 + v3)) + ((v4 + v5) + (v6 + v7));

        r += 32;
        p += 512;
    }

    // fold the 4 row-subgroups (lanes differing in bits 4,5 share columns)
    acc.x += __shfl_xor(acc.x, 16, 64);
    acc.y += __shfl_xor(acc.y, 16, 64);
    acc.z += __shfl_xor(acc.z, 16, 64);
    acc.w += __shfl_xor(acc.w, 16, 64);
    acc.x += __shfl_xor(acc.x, 32, 64);
    acc.y += __shfl_xor(acc.y, 32, 64);
    acc.z += __shfl_xor(acc.z, 32, 64);
    acc.w += __shfl_xor(acc.w, 32, 64);

    if (t < 16) {
        const float inv = (count > 0) ? (1.0f / (float)count) : 0.0f;
        *reinterpret_cast<f4*>(out + (size_t)s * 64 + c4) = acc * inv;
    }
}

extern "C" void kernel_launch(void* const* d_in, const int* in_sizes, int n_in,
                              void* d_out, int out_size, void* d_ws, size_t ws_size,
                              hipStream_t stream) {
    const float* values  = (const float*)d_in[0];
    const int*   seg_ids = (const int*)d_in[1];
    float*       out     = (float*)d_out;
    int*         offs    = (int*)d_ws;   // (N+1) ints = ~200 KB

    const int E = in_sizes[1];        // rows (= len(segment_ids))
    const int N = out_size / 64;      // segments (D = 64)

    const int quads = (E + 3) / 4;
    const int nblk  = (N + WPB - 1) / WPB;

    seg_bounds_kernel<<<dim3((quads + 255) / 256), dim3(256), 0, stream>>>(seg_ids, offs, E, N);
    seg_mean_kernel<<<dim3(nblk), dim3(256), 0, stream>>>(values, offs, out, N);
}